// Round 1
// baseline (428.245 us; speedup 1.0000x reference)
//
#include <hip/hip_runtime.h>
#include <stdint.h>
#include <stddef.h>

#define OBS 128
#define F1D 256
#define HD  128
#define NA  18
#define TT  128
#define BB  1024
#define NN  (TT*BB)
#define LOG2E 1.442695041f

typedef __attribute__((ext_vector_type(8))) short short8;
typedef __attribute__((ext_vector_type(4))) float f32x4;

__device__ __forceinline__ unsigned short f2bf(float f) {
  union { float f; uint32_t u; } v; v.f = f;
  uint32_t u = v.u;
  u += 0x7fffu + ((u >> 16) & 1u);   // RNE
  return (unsigned short)(u >> 16);
}
__device__ __forceinline__ float bf2f(uint32_t hu) {
  union { uint32_t u; float f; } v; v.u = hu << 16;
  return v.f;
}
__device__ __forceinline__ f32x4 mfma16(short8 a, short8 b, f32x4 c) {
  return __builtin_amdgcn_mfma_f32_16x16x32_bf16(a, b, c, 0, 0, 0);
}
// f32 -> bf16 fragment (8 consecutive, scaled)
__device__ __forceinline__ short8 cvt8(const float* p, float sc) {
  float4 a = *(const float4*)p;
  float4 b = *(const float4*)(p + 4);
  union { unsigned short u[8]; short8 s; } o;
  o.u[0]=f2bf(a.x*sc); o.u[1]=f2bf(a.y*sc); o.u[2]=f2bf(a.z*sc); o.u[3]=f2bf(a.w*sc);
  o.u[4]=f2bf(b.x*sc); o.u[5]=f2bf(b.y*sc); o.u[6]=f2bf(b.z*sc); o.u[7]=f2bf(b.w*sc);
  return o.s;
}
// pin: empty volatile asm with tied SCALAR "+v" operands (R6/R7 lessons).
__device__ __forceinline__ short8 pin(short8 v) {
  int4 i = *(int4*)&v;
  asm volatile("" : "+v"(i.x), "+v"(i.y), "+v"(i.z), "+v"(i.w));
  return *(short8*)&i;
}

// R10: LDS-only barrier. __syncthreads() emits s_waitcnt vmcnt(0) lgkmcnt(0)
// before s_barrier, draining the per-step global feat loads/stores that need
// NO barrier ordering (pure per-thread dataflow; compiler vmcnt-waits before
// register use). Only the LDS ping-pong needs ordering -> wait lgkm only.
// "memory" clobber on both sides keeps LDS ops from migrating across.
__device__ __forceinline__ void bar_lds() {
  asm volatile("s_waitcnt lgkmcnt(0)" ::: "memory");
  __builtin_amdgcn_s_barrier();
  asm volatile("" ::: "memory");
}

// One WG = (branch, 8-batch-row slice). Fully self-contained.
// Phase A: feature MLP; Phase B: masked LSTM (M=8 stride-2); Phase C: heads
// (R9: Phase C GEMM head. R10: lgkm-only barriers in all hot loops; full
//  __syncthreads() kept only at phase transitions where cross-thread global
//  RAW exists (A->B feat, B->C h-history). t=0 dummy h-store removed: without
//  vmcnt drains, same-address stores from steps 0/1 are not order-guaranteed.)
__global__ __launch_bounds__(512, 2) void fused_kernel(
    const float* __restrict__ x, const int* __restrict__ done,
    const int* __restrict__ action,
    const float* __restrict__ aw1, const float* __restrict__ ab1,
    const float* __restrict__ aw2, const float* __restrict__ ab2,
    const float* __restrict__ aflnw, const float* __restrict__ aflnb,
    const float* __restrict__ awih, const float* __restrict__ awhh,
    const float* __restrict__ a_b,
    const float* __restrict__ alnw, const float* __restrict__ alnb,
    const float* __restrict__ ahw, const float* __restrict__ ahb,
    const float* __restrict__ cw1, const float* __restrict__ cb1,
    const float* __restrict__ cw2, const float* __restrict__ cb2,
    const float* __restrict__ cflnw, const float* __restrict__ cflnb,
    const float* __restrict__ cwih, const float* __restrict__ cwhh,
    const float* __restrict__ c_b,
    const float* __restrict__ clnw, const float* __restrict__ clnb,
    const float* __restrict__ chw, const float* __restrict__ chb,
    const float* __restrict__ ah0, const float* __restrict__ ac0,
    const float* __restrict__ ch0, const float* __restrict__ cc0,
    unsigned short* __restrict__ featg, float* __restrict__ dout)
{
  int g = blockIdx.x;
  int br = g >> 7;
  int chunk = g & 127;
  int base8 = chunk * 8;

  const float* w1  = br ? cw1 : aw1;     // [256][128]
  const float* b1  = br ? cb1 : ab1;
  const float* w2  = br ? cw2 : aw2;     // [128][256]
  const float* b2  = br ? cb2 : ab2;
  const float* flw = br ? cflnw : aflnw;
  const float* flb = br ? cflnb : aflnb;
  const float* wih = br ? cwih : awih;   // [512][128]
  const float* whh = br ? cwhh : awhh;
  const float* gb  = br ? c_b : a_b;
  const float* h0  = br ? ch0 : ah0;
  const float* c0  = br ? cc0 : ac0;
  unsigned short* feat = featg + (size_t)br * NN * HD;

  // Phase A: xs(16K)+h1s(32K)+lnsum(2K)=50K  |  Phase C: hsn(32K)+cout(18K)
  __shared__ __align__(16) char smemA[51200];
  __shared__ float mls[(TT+1)*8];              // 1 - done, padded t=TT
  __shared__ unsigned short hlds[2][8*128];    // double-buffered masked h
  __shared__ float pa[HD], pb[HD], cws[HD];
  __shared__ float hbl[NA];
  __shared__ float cbsS;
  __shared__ int flagS;

  int tid = threadIdx.x;
  int w = tid >> 6, lane = tid & 63, q = lane >> 4, ln = lane & 15;
  int team = tid >> 8, t_tid = tid & 255, w4 = w & 3;

  // ================= Phase A: feature MLP =================
  {
    unsigned short* xst  = (unsigned short*)smemA + team*4096;           // 32*128
    unsigned short* h1st = (unsigned short*)(smemA + 16384) + team*8192; // 32*256
    float*          lnst = (float*)(smemA + 49152) + team*256;           // 32*8

    short8 b1f[4][4]; float b1v[4];
    #pragma unroll
    for (int ct = 0; ct < 4; ++ct) {
      int nn = w4*64 + ct*16 + ln;
      b1v[ct] = b1[nn];
      #pragma unroll
      for (int kf = 0; kf < 4; ++kf)
        b1f[ct][kf] = pin(cvt8(&w1[nn*OBS + kf*32 + q*8], 1.0f));
    }
    short8 b2f[2][8]; float b2v[2], lwv[2], lbv[2];
    #pragma unroll
    for (int nt = 0; nt < 2; ++nt) {
      int nn = w4*32 + nt*16 + ln;
      b2v[nt] = b2[nn]; lwv[nt] = flw[nn]; lbv[nt] = flb[nn];
      #pragma unroll
      for (int kf = 0; kf < 8; ++kf)
        b2f[nt][kf] = pin(cvt8(&w2[nn*F1D + kf*32 + q*8], 1.0f));
    }
    // tile = 4 timesteps x 8 batch rows = 32 rows; team handles tiles 2j+team
    float4 xr[4];
    #pragma unroll
    for (int s = 0; s < 4; ++s) {
      int e4 = t_tid + s*256;
      int r = e4 >> 5, c4 = e4 & 31;
      size_t grow = (size_t)(team*4 + (r>>3))*BB + base8 + (r&7);
      xr[s] = ((const float4*)x)[grow*32 + c4];
    }
    for (int j = 0; j < 16; ++j) {
      int jj = j*2 + team;
      #pragma unroll
      for (int s = 0; s < 4; ++s) {
        int e = (t_tid + s*256) * 4;
        int r = e >> 7, k = e & 127;
        int ad = r*128 + ((((k>>3) ^ (r&15)) << 3)) + (k&7);
        uint2 d;
        d.x = (uint32_t)f2bf(xr[s].x) | ((uint32_t)f2bf(xr[s].y) << 16);
        d.y = (uint32_t)f2bf(xr[s].z) | ((uint32_t)f2bf(xr[s].w) << 16);
        *(uint2*)&xst[ad] = d;
      }
      bar_lds();                       // B1: xs ready (LDS only)
      {
        int jjn = (j < 15) ? jj + 2 : jj;
        #pragma unroll
        for (int s = 0; s < 4; ++s) {
          int e4 = t_tid + s*256;
          int r = e4 >> 5, c4 = e4 & 31;
          size_t grow = (size_t)(jjn*4 + (r>>3))*BB + base8 + (r&7);
          xr[s] = ((const float4*)x)[grow*32 + c4];
        }
      }
      // ---- G1 ----
      short8 af[2][4];
      #pragma unroll
      for (int mt = 0; mt < 2; ++mt)
        #pragma unroll
        for (int kf = 0; kf < 4; ++kf)
          af[mt][kf] = *(const short8*)&xst[(mt*16 + ln)*128 + ((((kf<<2)|q) ^ ln) << 3)];
      #pragma unroll
      for (int ct = 0; ct < 4; ++ct) {
        int nn = w4*64 + ct*16 + ln;
        #pragma unroll
        for (int mt = 0; mt < 2; ++mt) {
          f32x4 acc = {b1v[ct], b1v[ct], b1v[ct], b1v[ct]};
          #pragma unroll
          for (int kf = 0; kf < 4; ++kf) acc = mfma16(af[mt][kf], b1f[ct][kf], acc);
          #pragma unroll
          for (int rg = 0; rg < 4; ++rg) {
            float v = acc[rg] > 0.0f ? acc[rg] : 0.0f;
            int rrow = mt*16 + q*4 + rg;
            h1st[rrow*256 + (((nn>>3) ^ (rrow&15)) << 3) + (nn&7)] = f2bf(v);
          }
        }
      }
      bar_lds();                       // B2: h1s ready (LDS only)
      // ---- G2 ----
      f32x4 acc2[2][2];
      #pragma unroll
      for (int mt = 0; mt < 2; ++mt) {
        short8 ah[8];
        #pragma unroll
        for (int kf = 0; kf < 8; ++kf)
          ah[kf] = *(const short8*)&h1st[(mt*16 + ln)*256 + ((((kf<<2)|q) ^ ln) << 3)];
        #pragma unroll
        for (int nt = 0; nt < 2; ++nt) {
          f32x4 acc = {b2v[nt], b2v[nt], b2v[nt], b2v[nt]};
          #pragma unroll
          for (int kf = 0; kf < 8; ++kf) acc = mfma16(ah[kf], b2f[nt][kf], acc);
          acc2[nt][mt] = acc;
        }
      }
      // ---- LN partials ----
      #pragma unroll
      for (int mt = 0; mt < 2; ++mt)
        #pragma unroll
        for (int rg = 0; rg < 4; ++rg) {
          float s = acc2[0][mt][rg] + acc2[1][mt][rg];
          float ssq = acc2[0][mt][rg]*acc2[0][mt][rg] + acc2[1][mt][rg]*acc2[1][mt][rg];
          #pragma unroll
          for (int m = 1; m < 16; m <<= 1) { s += __shfl_xor(s, m); ssq += __shfl_xor(ssq, m); }
          if (ln == 0) {
            int r = mt*16 + q*4 + rg;
            lnst[r*8 + w4*2]     = s;
            lnst[r*8 + w4*2 + 1] = ssq;
          }
        }
      bar_lds();                       // B3: lnsum ready (LDS only)
      #pragma unroll
      for (int mt = 0; mt < 2; ++mt)
        #pragma unroll
        for (int rg = 0; rg < 4; ++rg) {
          int r = mt*16 + q*4 + rg;
          float4 p0 = *(const float4*)&lnst[r*8];
          float4 p1 = *(const float4*)&lnst[r*8 + 4];
          float S  = p0.x + p0.z + p1.x + p1.z;
          float SS = p0.y + p0.w + p1.y + p1.w;
          float mu = S * (1.0f/128.0f);
          float var = SS * (1.0f/128.0f) - mu*mu;
          float rstd = rsqrtf(var + 1e-5f);
          size_t grow = (size_t)(jj*4 + (r>>3))*BB + base8 + (r&7);
          #pragma unroll
          for (int nt = 0; nt < 2; ++nt) {
            float t = (acc2[nt][mt][rg] - mu) * rstd * lwv[nt] + lbv[nt];
            if (t < 0.0f) t = 0.0f;
            feat[grow*HD + w4*32 + nt*16 + ln] = f2bf(t);
          }
        }
      bar_lds();                       // Bend (LDS only; feat stores stay in flight)
    }
  }

  // ================= Phase B: masked LSTM (M=8, stride-2 packing) =================
  int n = w*16 + ln;
  {
    short8 bfr[4][8]; float bias[4];
    #pragma unroll
    for (int g4 = 0; g4 < 4; ++g4) {
      int gn = g4*128 + n;
      float sc = (g4 == 2) ? -2.0f*LOG2E : -LOG2E;   // gate order i,f,g,o
      bias[g4] = gb[gn] * sc;
      #pragma unroll
      for (int kf = 0; kf < 8; ++kf) {
        const float* src = (kf < 4) ? &wih[gn*HD + kf*32 + q*8]
                                    : &whh[gn*HD + (kf-4)*32 + q*8];
        bfr[g4][kf] = pin(cvt8(src, sc));
      }
    }
    for (int i = tid; i < (TT+1)*8; i += 512)
      mls[i] = (i < TT*8) ? 1.0f - (float)done[(i>>3)*BB + base8 + (i&7)] : 1.0f;

    const int loff = (base8 + (ln>>1))*HD + q*8;   // A-row ln -> batch row ln>>1
    int soff[2], hoffw[2], haddr[4];
    #pragma unroll
    for (int j = 0; j < 2; ++j) {
      int r = q*2 + j;
      soff[j]  = (base8 + r)*HD + n;
      hoffw[j] = r*128 + (((n>>3) ^ r) << 3) + (n&7);
    }
    #pragma unroll
    for (int kf = 0; kf < 4; ++kf) {
      int rr = ln >> 1;
      haddr[kf] = rr*128 + ((((kf<<2)|q) ^ rr) << 3);
    }
    float hp[2], cp[2]; unsigned short hu_prev[2];
    #pragma unroll
    for (int j = 0; j < 2; ++j) {
      int b = base8 + q*2 + j;
      hp[j] = h0[b*HD + n];
      cp[j] = c0[b*HD + n];
      hu_prev[j] = 0;
    }
    // FULL barrier: drains Phase A feat stores (cross-thread global RAW for
    // the afr/fq reads below) and makes mls visible.
    __syncthreads();
    short8 afr[4], nfr[4];
    #pragma unroll
    for (int kf = 0; kf < 4; ++kf)
      afr[kf] = *(const short8*)&feat[loff + kf*32];    // feat[0]
    #pragma unroll
    for (int j = 0; j < 2; ++j) {
      float m = mls[q*2 + j];
      cp[j] *= m;
      hlds[0][hoffw[j]] = f2bf(hp[j] * m);
    }
    bar_lds();   // hlds[0] ready

#define LSTM_STEP(TTT, CUR, NXT, HB)                                           \
  {                                                                            \
    short8 hfr[4];                                                             \
    _Pragma("unroll")                                                          \
    for (int kf = 0; kf < 4; ++kf)                                             \
      hfr[kf] = *(const short8*)&hlds[HB][haddr[kf]];                          \
    if ((TTT) > 0) {                                                           \
      unsigned short* sq = feat + (size_t)((TTT) - 1) * (BB*HD);               \
      sq[soff[0]] = hu_prev[0];                                                \
      sq[soff[1]] = hu_prev[1];                                                \
    }                                                                          \
    int tn = ((TTT) + 1 < TT) ? (TTT) + 1 : TT - 1;                            \
    const unsigned short* fq = feat + (size_t)tn * (BB*HD);                    \
    _Pragma("unroll")                                                          \
    for (int kf = 0; kf < 4; ++kf)                                             \
      NXT[kf] = *(const short8*)&fq[loff + kf*32];                             \
    f32x4 a0 = {bias[0],bias[0],bias[0],bias[0]};                              \
    f32x4 a1 = {bias[1],bias[1],bias[1],bias[1]};                              \
    f32x4 a2 = {bias[2],bias[2],bias[2],bias[2]};                              \
    f32x4 a3 = {bias[3],bias[3],bias[3],bias[3]};                              \
    _Pragma("unroll")                                                          \
    for (int kf = 0; kf < 4; ++kf) {                                           \
      a0 = mfma16(CUR[kf], bfr[0][kf], a0);                                    \
      a1 = mfma16(CUR[kf], bfr[1][kf], a1);                                    \
      a2 = mfma16(CUR[kf], bfr[2][kf], a2);                                    \
      a3 = mfma16(CUR[kf], bfr[3][kf], a3);                                    \
    }                                                                          \
    _Pragma("unroll")                                                          \
    for (int kf = 0; kf < 4; ++kf) {                                           \
      a0 = mfma16(hfr[kf], bfr[0][4+kf], a0);                                  \
      a1 = mfma16(hfr[kf], bfr[1][4+kf], a1);                                  \
      a2 = mfma16(hfr[kf], bfr[2][4+kf], a2);                                  \
      a3 = mfma16(hfr[kf], bfr[3][4+kf], a3);                                  \
    }                                                                          \
    float2 mn = *(const float2*)&mls[((TTT)+1)*8 + q*2];                       \
    _Pragma("unroll")                                                          \
    for (int j = 0; j < 2; ++j) {                                              \
      int rg = j*2;  /* C rows duplicated pairwise; even reg = valid copy */   \
      float si = __builtin_amdgcn_rcpf(1.0f + __builtin_amdgcn_exp2f(a0[rg])); \
      float sf = __builtin_amdgcn_rcpf(1.0f + __builtin_amdgcn_exp2f(a1[rg])); \
      float tg = __builtin_fmaf(2.0f,                                          \
                   __builtin_amdgcn_rcpf(1.0f + __builtin_amdgcn_exp2f(a2[rg])), -1.0f); \
      float so = __builtin_amdgcn_rcpf(1.0f + __builtin_amdgcn_exp2f(a3[rg])); \
      float cn = __builtin_fmaf(sf, cp[j], si*tg);                             \
      float th = __builtin_fmaf(2.0f,                                          \
                   __builtin_amdgcn_rcpf(1.0f + __builtin_amdgcn_exp2f(-2.0f*LOG2E*cn)), -1.0f); \
      float hn = so * th;                                                      \
      unsigned short hu = f2bf(hn);                                            \
      hu_prev[j] = hu;                                                         \
      bool live = ((&mn.x)[j] != 0.0f);                                        \
      cp[j] = live ? cn : 0.0f;                                                \
      hp[j] = hn;                                                              \
      hlds[(HB)^1][hoffw[j]] = live ? hu : (unsigned short)0;                  \
    }                                                                          \
    bar_lds();                                                                 \
  }

    for (int t = 0; t < TT; t += 2) {
      LSTM_STEP(t,   afr, nfr, 0)
      LSTM_STEP(t+1, nfr, afr, 1)
    }
#undef LSTM_STEP

    {
      unsigned short* sq = feat + (size_t)(TT-1)*(BB*HD);
      sq[soff[0]] = hu_prev[0];
      sq[soff[1]] = hu_prev[1];
    }
    {
      float* outh = dout + (size_t)(4 + br*2) * NN;
      float* outc = dout + (size_t)(5 + br*2) * NN;
      #pragma unroll
      for (int j = 0; j < 2; ++j) {
        int b = base8 + q*2 + j;
        outh[b*HD + n] = hp[j];
        outc[b*HD + n] = cp[j];
      }
    }
  }

  // ================= Phase C: heads (GEMM actor / inline critic) =================
  if (tid == 0) flagS = 0;
  if (tid < HD) {
    pa[tid] = br ? clnw[tid] : alnw[tid];
    pb[tid] = br ? clnb[tid] : alnb[tid];
    if (br) cws[tid] = chw[tid];
  }
  int localf = 0;
  if (br == 0) {
    if (tid < NA) hbl[tid] = ahb[tid];
    for (int i = 2*tid + 1; i < 4096; i += 1024) localf |= action[i];
  } else if (tid == 0) cbsS = chb[0];
  __syncthreads();   // FULL: params + flagS=0 visible; LSTM h-stores drained
  if (localf) flagS = 1;
  bar_lds();

  int sub = tid & 3, kidx = tid >> 2;
  if (br == 0) {
    unsigned short* hsn = (unsigned short*)smemA;   // [128][128] bf16 swizzled
    float* co = (float*)(smemA + 32768);            // [128][36] f32
    // head B-frags: actions 0..17, zero-padded to 32 rows; pinned
    short8 hbf[2][4];
    #pragma unroll
    for (int nt = 0; nt < 2; ++nt) {
      int nn = nt*16 + ln;
      #pragma unroll
      for (int kf = 0; kf < 4; ++kf) {
        short8 z = {0,0,0,0,0,0,0,0};
        hbf[nt][kf] = (nn < NA) ? pin(cvt8(&ahw[nn*HD + kf*32 + q*8], 1.0f)) : z;
      }
    }
    int fl = flagS;
    for (int ch = 0; ch < 8; ++ch) {
      // --- stage A: LN (4 lanes/row) -> hsn bf16 swizzled ---
      {
        int k = ch*128 + kidx;
        int rrow = (k >> 3)*BB + base8 + (k & 7);
        const unsigned short* hp2 = feat + (size_t)rrow*HD + sub*32;
        uint4 d0 = *(const uint4*)hp2;
        uint4 d1 = *(const uint4*)(hp2 + 8);
        uint4 d2 = *(const uint4*)(hp2 + 16);
        uint4 d3 = *(const uint4*)(hp2 + 24);
        float nv[32];
        #define UP(W_, B_) { nv[B_] = bf2f((W_) & 0xffffu); nv[(B_)+1] = bf2f((W_) >> 16); }
        UP(d0.x,0) UP(d0.y,2) UP(d0.z,4) UP(d0.w,6)
        UP(d1.x,8) UP(d1.y,10) UP(d1.z,12) UP(d1.w,14)
        UP(d2.x,16) UP(d2.y,18) UP(d2.z,20) UP(d2.w,22)
        UP(d3.x,24) UP(d3.y,26) UP(d3.z,28) UP(d3.w,30)
        #undef UP
        float s = 0.0f, ssq = 0.0f;
        #pragma unroll
        for (int j = 0; j < 32; ++j) { s += nv[j]; ssq += nv[j]*nv[j]; }
        s += __shfl_xor(s, 1); ssq += __shfl_xor(ssq, 1);
        s += __shfl_xor(s, 2); ssq += __shfl_xor(ssq, 2);
        float mu = s * (1.0f/128.0f);
        float var = ssq * (1.0f/128.0f) - mu*mu;
        float rstd = rsqrtf(var + 1e-5f);
        #pragma unroll
        for (int cc = 0; cc < 4; ++cc) {
          unsigned short ob[8];
          #pragma unroll
          for (int j = 0; j < 8; ++j) {
            int c = sub*32 + cc*8 + j;
            ob[j] = f2bf((nv[cc*8+j] - mu) * rstd * pa[c] + pb[c]);
          }
          int c8 = sub*4 + cc;
          *(short8*)&hsn[kidx*128 + ((c8 ^ (kidx & 15)) << 3)] = *(short8*)ob;
        }
      }
      bar_lds();
      // --- stage B: logits GEMM (wave w -> rows w*16..+16) ---
      {
        short8 afh[4];
        #pragma unroll
        for (int kf = 0; kf < 4; ++kf)
          afh[kf] = *(const short8*)&hsn[(w*16 + ln)*128 + ((((kf<<2)|q) ^ ln) << 3)];
        #pragma unroll
        for (int nt = 0; nt < 2; ++nt) {
          f32x4 acc = {0.0f, 0.0f, 0.0f, 0.0f};
          #pragma unroll
          for (int kf = 0; kf < 4; ++kf) acc = mfma16(afh[kf], hbf[nt][kf], acc);
          #pragma unroll
          for (int rg = 0; rg < 4; ++rg)
            co[(w*16 + q*4 + rg)*36 + nt*16 + ln] = acc[rg];
        }
      }
      bar_lds();
      // --- stage C: softmax/logp/entropy (1 thread/row, tid<128) ---
      if (tid < 128) {
        int k = ch*128 + tid;
        int rrow = (k >> 3)*BB + base8 + (k & 7);
        int act = fl ? action[rrow] : (int)(((const long long*)action)[rrow]);
        dout[rrow] = (float)act;
        int aidx = act < 0 ? 0 : (act > NA-1 ? NA-1 : act);
        float lg[NA];
        #pragma unroll
        for (int a = 0; a < NA; ++a) lg[a] = co[tid*36 + a] + hbl[a];
        float mx = lg[0];
        #pragma unroll
        for (int a = 1; a < NA; ++a) mx = fmaxf(mx, lg[a]);
        float se = 0.0f;
        #pragma unroll
        for (int a = 0; a < NA; ++a) se += __expf(lg[a] - mx);
        float lse = __logf(se);
        float lpa = 0.0f, ent = 0.0f;
        #pragma unroll
        for (int a = 0; a < NA; ++a) {
          float lp = lg[a] - mx - lse;
          ent -= __expf(lp) * lp;
          lpa += (a == aidx) ? lp : 0.0f;
        }
        dout[(size_t)NN + rrow] = lpa;
        dout[(size_t)2*NN + rrow] = ent;
      }
      bar_lds();
    }
  } else {
    // critic: inline LN + dot, no GEMM, no barriers needed
    for (int ch = 0; ch < 8; ++ch) {
      int k = ch*128 + kidx;
      int rrow = (k >> 3)*BB + base8 + (k & 7);
      const unsigned short* hp2 = feat + (size_t)rrow*HD + sub*32;
      uint4 d0 = *(const uint4*)hp2;
      uint4 d1 = *(const uint4*)(hp2 + 8);
      uint4 d2 = *(const uint4*)(hp2 + 16);
      uint4 d3 = *(const uint4*)(hp2 + 24);
      float nv[32];
      #define UP(W_, B_) { nv[B_] = bf2f((W_) & 0xffffu); nv[(B_)+1] = bf2f((W_) >> 16); }
      UP(d0.x,0) UP(d0.y,2) UP(d0.z,4) UP(d0.w,6)
      UP(d1.x,8) UP(d1.y,10) UP(d1.z,12) UP(d1.w,14)
      UP(d2.x,16) UP(d2.y,18) UP(d2.z,20) UP(d2.w,22)
      UP(d3.x,24) UP(d3.y,26) UP(d3.z,28) UP(d3.w,30)
      #undef UP
      float s = 0.0f, ssq = 0.0f;
      #pragma unroll
      for (int j = 0; j < 32; ++j) { s += nv[j]; ssq += nv[j]*nv[j]; }
      s += __shfl_xor(s, 1); ssq += __shfl_xor(ssq, 1);
      s += __shfl_xor(s, 2); ssq += __shfl_xor(ssq, 2);
      float mu = s * (1.0f/128.0f);
      float var = ssq * (1.0f/128.0f) - mu*mu;
      float rstd = rsqrtf(var + 1e-5f);
      float dot = 0.0f;
      #pragma unroll
      for (int j = 0; j < 32; ++j) {
        int c = sub*32 + j;
        dot += ((nv[j] - mu) * rstd * pa[c] + pb[c]) * cws[c];
      }
      dot += __shfl_xor(dot, 1);
      dot += __shfl_xor(dot, 2);
      if (sub == 0) dout[(size_t)3*NN + rrow] = dot + cbsS;
    }
  }
}

extern "C" void kernel_launch(void* const* d_in, const int* in_sizes, int n_in,
                              void* d_out, int out_size, void* d_ws, size_t ws_size,
                              hipStream_t stream) {
  (void)in_sizes; (void)n_in; (void)out_size; (void)ws_size;
  const float* x    = (const float*)d_in[0];
  const float* ah0  = (const float*)d_in[1];
  const float* ac0  = (const float*)d_in[2];
  const float* ch0  = (const float*)d_in[3];
  const float* cc0  = (const float*)d_in[4];
  const int*   done = (const int*)d_in[5];
  const int*   act  = (const int*)d_in[6];
  const float* aw1  = (const float*)d_in[7];
  const float* ab1  = (const float*)d_in[8];
  const float* aw2  = (const float*)d_in[9];
  const float* ab2  = (const float*)d_in[10];
  const float* aflnw= (const float*)d_in[11];
  const float* aflnb= (const float*)d_in[12];
  const float* awih = (const float*)d_in[13];
  const float* awhh = (const float*)d_in[14];
  const float* a_b  = (const float*)d_in[15];
  const float* alnw = (const float*)d_in[16];
  const float* alnb = (const float*)d_in[17];
  const float* ahw  = (const float*)d_in[18];
  const float* ahb  = (const float*)d_in[19];
  const float* cw1  = (const float*)d_in[20];
  const float* cb1  = (const float*)d_in[21];
  const float* cw2  = (const float*)d_in[22];
  const float* cb2  = (const float*)d_in[23];
  const float* cflnw= (const float*)d_in[24];
  const float* cflnb= (const float*)d_in[25];
  const float* cwih = (const float*)d_in[26];
  const float* cwhh = (const float*)d_in[27];
  const float* c_b  = (const float*)d_in[28];
  const float* clnw = (const float*)d_in[29];
  const float* clnb = (const float*)d_in[30];
  const float* chw  = (const float*)d_in[31];
  const float* chb  = (const float*)d_in[32];

  unsigned short* featb = (unsigned short*)d_ws;   // [2][NN*HD] bf16
  float* out = (float*)d_out;

  fused_kernel<<<256, 512, 0, stream>>>(
      x, done, act,
      aw1, ab1, aw2, ab2, aflnw, aflnb, awih, awhh, a_b, alnw, alnb, ahw, ahb,
      cw1, cb1, cw2, cb2, cflnw, cflnb, cwih, cwhh, c_b, clnw, clnb, chw, chb,
      ah0, ac0, ch0, cc0,
      featb, out);
}